// Round 19
// baseline (41.570 us; speedup 1.0000x reference)
//
#include <hip/hip_runtime.h>
#include <hip/hip_bf16.h>

#define B_  4
#define C_  640
#define H_  64
#define W_  64
#define G_  16          // channel groups (one wave each)
#define CPG 40          // channels per wave: G_*CPG == C_
#define NT  1024
#define GRP 66          // group-dim stride (uints): 64 groups + 2 pad

__device__ __forceinline__ unsigned short f2bf(float f) {
    __hip_bfloat16 h = __float2bfloat16(f);
    return __builtin_bit_cast(unsigned short, h);
}
__device__ __forceinline__ unsigned int packbf(float a, float b) {
    return (unsigned)f2bf(a) | ((unsigned)f2bf(b) << 16);
}
__device__ __forceinline__ float lo16(unsigned u) {
    return __builtin_bit_cast(float, u << 16);
}
__device__ __forceinline__ float hi16(unsigned u) {
    return __builtin_bit_cast(float, u & 0xffff0000u);
}

__global__ __launch_bounds__(NT, 4) void nca_fused(
    const float* __restrict__ Ft,
    const float* __restrict__ Fwp,
    const float* __restrict__ mask,
    const float* __restrict__ cw,
    const float* __restrict__ cb,
    float* __restrict__ out)
{
    __shared__ float lds_cw[2 * C_];              // 5 KB
    __shared__ float lds_msk[3][W_];              // 0.75 KB
    __shared__ unsigned int lds_simb[9][32][GRP]; // 74.25 KB  bf16-pair sim partials
    __shared__ unsigned int lds_PTb[4][32][GRP];  // 33 KB     bf16-pair P/T partials
    __shared__ float lds_attn[W_][9];             // 2.25 KB
    __shared__ float lds_Pf[4][W_];               // 1 KB
    __shared__ float lds_lam[W_];                 // 0.25 KB
    // total ~116.5 KB (< 160 KB/CU, 1 block/CU)

    const int t   = threadIdx.x;
    const int l   = t & 63;
    const int g   = t >> 6;        // wave id = channel group
    const int sub = l >> 4;        // channel subgroup 0..3
    const int l16 = l & 15;
    const int w0  = l16 * 4;       // first pixel column of this lane

    // XCD-aware swizzle: XCD x owns rows [x*8, x*8+8) for all batches.
    const int n    = blockIdx.x + gridDim.x * blockIdx.y;
    const int slot = n >> 3;
    const int h = (n & 7) * 8 + (slot & 7);
    const int b = slot >> 3;

    const int hm = (h > 0) ? (h - 1) : 0;
    const int hp = (h < H_ - 1) ? (h + 1) : (H_ - 1);
    const size_t cs = (size_t)H_ * W_;
    const int c0 = g * CPG;

    for (int i = t; i < 2 * C_; i += NT) lds_cw[i] = cw[i];
    if (t < 3 * W_) {
        const int r = t >> 6, col = t & 63;
        const int row = (r == 0) ? hm : ((r == 1) ? h : hp);
        lds_msk[r][col] = mask[((size_t)b * H_ + row) * W_ + col];
    }
    __syncthreads();

    const size_t base = (size_t)(b * C_ + c0) * H_;
    const size_t lo   = (size_t)sub * cs + w0;
    const float* ftp = Ft  + (base + h ) * W_ + lo;
    const float* q0p = Fwp + (base + hm) * W_ + lo;
    const float* q1p = Fwp + (base + h ) * W_ + lo;
    const float* q2p = Fwp + (base + hp) * W_ + lo;

    // ---- Pass A + P/T fused: ONE walk, displaced edges (2 shfl/iter) ------
    // acc[(3r+cc)*4+px]; edge slots (cc=-1,px0)=12r+0 and (cc=+1,px3)=12r+11
    // are accumulated DISPLACED in dA/dB (only ft is shuffled, once per iter),
    // realigned after the loop. Replicate-pad: a[0]==a[4], a[11]==a[7].
    float acc[36], Pp[12], T4[4], dA[3], dB[3];
    #pragma unroll
    for (int i = 0; i < 36; ++i) acc[i] = 0.f;
    #pragma unroll
    for (int i = 0; i < 12; ++i) Pp[i] = 0.f;
    #pragma unroll
    for (int i = 0; i < 4; ++i) T4[i] = 0.f;
    #pragma unroll
    for (int i = 0; i < 3; ++i) { dA[i] = 0.f; dB[i] = 0.f; }

    #pragma unroll 4
    for (int k = 0; k < CPG; k += 4) {
        const size_t off = (size_t)k * cs;
        const float4 ft4 = *(const float4*)(ftp + off);
        const float4 r0  = *(const float4*)(q0p + off);
        const float4 r1  = *(const float4*)(q1p + off);
        const float4 r2  = *(const float4*)(q2p + off);
        const float ftxN = __shfl_down(ft4.x, 1, 64);   // lane l+1's ft4.x
        const float ftwP = __shfl_up  (ft4.w, 1, 64);   // lane l-1's ft4.w
        #define ROWA(r4, A, ri)                                   \
            acc[A+1] = fmaf(ft4.y, r4.x, acc[A+1]);               \
            acc[A+2] = fmaf(ft4.z, r4.y, acc[A+2]);               \
            acc[A+3] = fmaf(ft4.w, r4.z, acc[A+3]);               \
            acc[A+4] = fmaf(ft4.x, r4.x, acc[A+4]);               \
            acc[A+5] = fmaf(ft4.y, r4.y, acc[A+5]);               \
            acc[A+6] = fmaf(ft4.z, r4.z, acc[A+6]);               \
            acc[A+7] = fmaf(ft4.w, r4.w, acc[A+7]);               \
            acc[A+8] = fmaf(ft4.x, r4.y, acc[A+8]);               \
            acc[A+9] = fmaf(ft4.y, r4.z, acc[A+9]);               \
            acc[A+10]= fmaf(ft4.z, r4.w, acc[A+10]);              \
            dA[ri] = fmaf(ftxN, r4.w, dA[ri]);                    \
            dB[ri] = fmaf(ftwP, r4.x, dB[ri]);
        ROWA(r0, 0,  0)
        ROWA(r1, 12, 1)
        ROWA(r2, 24, 2)
        #undef ROWA
        const int c = c0 + k + sub;
        const float wF = lds_cw[c];
        const float wT = lds_cw[C_ + c];
        Pp[0] = fmaf(wF, r0.x, Pp[0]); Pp[1]  = fmaf(wF, r0.y, Pp[1]);
        Pp[2] = fmaf(wF, r0.z, Pp[2]); Pp[3]  = fmaf(wF, r0.w, Pp[3]);
        Pp[4] = fmaf(wF, r1.x, Pp[4]); Pp[5]  = fmaf(wF, r1.y, Pp[5]);
        Pp[6] = fmaf(wF, r1.z, Pp[6]); Pp[7]  = fmaf(wF, r1.w, Pp[7]);
        Pp[8] = fmaf(wF, r2.x, Pp[8]); Pp[9]  = fmaf(wF, r2.y, Pp[9]);
        Pp[10]= fmaf(wF, r2.z, Pp[10]);Pp[11] = fmaf(wF, r2.w, Pp[11]);
        T4[0] = fmaf(wT, ft4.x, T4[0]); T4[1] = fmaf(wT, ft4.y, T4[1]);
        T4[2] = fmaf(wT, ft4.z, T4[2]); T4[3] = fmaf(wT, ft4.w, T4[3]);
    }

    // realign displaced edge sums to the owning lane (once, 6 shuffles)
    #pragma unroll
    for (int r = 0; r < 3; ++r) {
        const float eL = __shfl_up  (dA[r], 1, 64);   // lane l-1's dA = my a[0]
        const float eR = __shfl_down(dB[r], 1, 64);   // lane l+1's dB = my a[11]
        acc[12*r + 0]  = (l16 == 0)  ? acc[12*r + 4] : eL;   // replicate pad
        acc[12*r + 11] = (l16 == 15) ? acc[12*r + 7] : eR;
    }

    // ---- pack bf16 pairs, direct conflict-free LDS writes (no butterfly) --
    {
        const int g4s = g * 4 + sub;        // channel-group 0..63
        #pragma unroll
        for (int q = 0; q < 9; ++q) {
            lds_simb[q][2 * l16 + 0][g4s] = packbf(acc[q * 4 + 0], acc[q * 4 + 1]);
            lds_simb[q][2 * l16 + 1][g4s] = packbf(acc[q * 4 + 2], acc[q * 4 + 3]);
        }
        #pragma unroll
        for (int r = 0; r < 3; ++r) {
            lds_PTb[r][2 * l16 + 0][g4s] = packbf(Pp[r * 4 + 0], Pp[r * 4 + 1]);
            lds_PTb[r][2 * l16 + 1][g4s] = packbf(Pp[r * 4 + 2], Pp[r * 4 + 3]);
        }
        lds_PTb[3][2 * l16 + 0][g4s] = packbf(T4[0], T4[1]);
        lds_PTb[3][2 * l16 + 1][g4s] = packbf(T4[2], T4[3]);
    }
    __syncthreads();

    // ---- reduce 64 groups + mask (288 thr) ; P/T reduce (128 thr) ---------
    if (t < 288) {
        const int q = t / 32, wp = t % 32;        // ww pair (2wp, 2wp+1)
        float s0 = 0.f, s1 = 0.f;
        #pragma unroll
        for (int i = 0; i < 32; ++i) {
            const uint2 u = *(const uint2*)&lds_simb[q][wp][2 * i];
            s0 += lo16(u.x) + lo16(u.y);
            s1 += hi16(u.x) + hi16(u.y);
        }
        s0 *= 0.03952847075210474f;               // 1/sqrt(640)
        s1 *= 0.03952847075210474f;
        const int r = q / 3, j = q % 3;
        const int ww0 = 2 * wp, ww1 = 2 * wp + 1;
        int cA = ww0 + j - 1; cA = cA < 0 ? 0 : (cA > W_ - 1 ? W_ - 1 : cA);
        int cB = ww1 + j - 1; cB = cB < 0 ? 0 : (cB > W_ - 1 ? W_ - 1 : cB);
        if (lds_msk[r][cA] == 1.0f) s0 = -1e9f;
        if (lds_msk[r][cB] == 1.0f) s1 = -1e9f;
        lds_attn[ww0][q] = s0;
        lds_attn[ww1][q] = s1;
    } else if (t < 288 + 128) {
        const int idx = t - 288;
        const int r = idx / 32, wp = idx % 32;
        float s0 = 0.f, s1 = 0.f;
        #pragma unroll
        for (int i = 0; i < 32; ++i) {
            const uint2 u = *(const uint2*)&lds_PTb[r][wp][2 * i];
            s0 += lo16(u.x) + lo16(u.y);
            s1 += hi16(u.x) + hi16(u.y);
        }
        lds_Pf[r][2 * wp]     = s0;
        lds_Pf[r][2 * wp + 1] = s1;
    }
    __syncthreads();

    // ---- softmax per pixel + lambda via P-trick ---------------------------
    if (t < W_) {
        float v[9];
        float mx = -3e38f;
        bool valid = false;
        #pragma unroll
        for (int q = 0; q < 9; ++q) {
            v[q] = lds_attn[t][q];
            if (v[q] > -5e8f) valid = true;
            mx = fmaxf(mx, v[q]);
        }
        float a9[9];
        if (!valid) {
            #pragma unroll
            for (int q = 0; q < 9; ++q) a9[q] = 0.f;
        } else {
            float sum = 0.f;
            #pragma unroll
            for (int q = 0; q < 9; ++q) { a9[q] = expf(v[q] - mx); sum += a9[q]; }
            const float inv = 1.f / sum;
            #pragma unroll
            for (int q = 0; q < 9; ++q) a9[q] *= inv;
        }
        #pragma unroll
        for (int q = 0; q < 9; ++q) lds_attn[t][q] = a9[q];

        float lamF = 0.f;
        #pragma unroll
        for (int r = 0; r < 3; ++r)
            #pragma unroll
            for (int j = 0; j < 3; ++j) {
                int col = t + j - 1;
                col = col < 0 ? 0 : (col > W_ - 1 ? W_ - 1 : col);
                lamF = fmaf(a9[r * 3 + j], lds_Pf[r][col], lamF);
            }
        const float d = lds_Pf[3][t] + lamF + cb[0];
        lds_lam[t] = 1.f / (1.f + expf(-d));
    }
    __syncthreads();

    // ---- Pass BC: displaced edges (2 shfl/iter), blend + store ------------
    float at[36];
    #pragma unroll
    for (int px = 0; px < 4; ++px)
        #pragma unroll
        for (int q = 0; q < 9; ++q) at[px * 9 + q] = lds_attn[w0 + px][q];
    float lam4[4], oml4[4];
    #pragma unroll
    for (int px = 0; px < 4; ++px) {
        lam4[px] = lds_lam[w0 + px];
        oml4[px] = 1.f - lam4[px];
    }

    // loop-invariant edge weights: neighbor-lane attn (pre-shuffled) + folds
    float atn0[3], atp3[3], atx0[3], atx3[3];
    #pragma unroll
    for (int r = 0; r < 3; ++r) {
        atn0[r] = __shfl_down(at[3 * r], 1, 64);            // l+1's px0 cc=-1 w
        atp3[r] = __shfl_up  (at[27 + 3 * r + 2], 1, 64);   // l-1's px3 cc=+1 w
        atx0[r] = at[3 * r + 1]      + ((l16 == 0)  ? at[3 * r]          : 0.f);
        atx3[r] = at[27 + 3 * r + 1] + ((l16 == 15) ? at[27 + 3 * r + 2] : 0.f);
    }

    float* outp = out + (base + h) * W_ + lo;
    #pragma unroll 2
    for (int k = 0; k < CPG; k += 4) {
        const size_t off = (size_t)k * cs;
        const float4 ft4 = *(const float4*)(ftp + off);
        const float4 r0  = *(const float4*)(q0p + off);
        const float4 r1  = *(const float4*)(q1p + off);
        const float4 r2  = *(const float4*)(q2p + off);
        // displaced edge sums (one value per side, 3 rows collapsed)
        const float DL = atn0[0]*r0.w + atn0[1]*r1.w + atn0[2]*r2.w; // -> l+1 fwv0
        const float DR = atp3[0]*r0.x + atp3[1]*r1.x + atp3[2]*r2.x; // -> l-1 fwv3
        const float eL = __shfl_up  (DL, 1, 64);
        const float eR = __shfl_down(DR, 1, 64);
        float fwv0 = atx0[0]*r0.x + at[2]*r0.y
                   + atx0[1]*r1.x + at[5]*r1.y
                   + atx0[2]*r2.x + at[8]*r2.y
                   + ((l16 == 0) ? 0.f : eL);
        float fwv1 = at[ 9]*r0.x + at[10]*r0.y + at[11]*r0.z
                   + at[12]*r1.x + at[13]*r1.y + at[14]*r1.z
                   + at[15]*r2.x + at[16]*r2.y + at[17]*r2.z;
        float fwv2 = at[18]*r0.y + at[19]*r0.z + at[20]*r0.w
                   + at[21]*r1.y + at[22]*r1.z + at[23]*r1.w
                   + at[24]*r2.y + at[25]*r2.z + at[26]*r2.w;
        float fwv3 = at[27]*r0.z + atx3[0]*r0.w
                   + at[30]*r1.z + atx3[1]*r1.w
                   + at[33]*r2.z + atx3[2]*r2.w
                   + ((l16 == 15) ? 0.f : eR);
        float4 o;
        o.x = lam4[0] * ft4.x + oml4[0] * fwv0;
        o.y = lam4[1] * ft4.y + oml4[1] * fwv1;
        o.z = lam4[2] * ft4.z + oml4[2] * fwv2;
        o.w = lam4[3] * ft4.w + oml4[3] * fwv3;
        *(float4*)(outp + off) = o;
    }
}

extern "C" void kernel_launch(void* const* d_in, const int* in_sizes, int n_in,
                              void* d_out, int out_size, void* d_ws, size_t ws_size,
                              hipStream_t stream) {
    const float* Ft   = (const float*)d_in[0];
    const float* Fwp  = (const float*)d_in[1];
    const float* mask = (const float*)d_in[2];
    const float* cw   = (const float*)d_in[3];
    const float* cb   = (const float*)d_in[4];
    float* out = (float*)d_out;

    dim3 grid(H_, B_);   // 256 blocks == 256 CUs
    dim3 block(NT);
    nca_fused<<<grid, block, 0, stream>>>(Ft, Fwp, mask, cw, cb, out);
}